// Round 3
// baseline (2215.690 us; speedup 1.0000x reference)
//
#include <hip/hip_runtime.h>
#include <hip/hip_bf16.h>
#include <math.h>

#define N_NODES 50000
#define N_EDGES 800000
#define EMB 128
#define LH 256
#define NSENT 2048
#define MAXLEN 32
#define SCAN_NB 196   // ceil(50000/256)

typedef __attribute__((ext_vector_type(8))) short short8;
typedef __attribute__((ext_vector_type(4))) float f32x4;

__device__ __forceinline__ unsigned short f2bf_u(float f) {
    __hip_bfloat16 h = __float2bfloat16(f);
    return *reinterpret_cast<unsigned short*>(&h);
}
__device__ __forceinline__ float bfu2f(unsigned short u) {
    unsigned int x = ((unsigned int)u) << 16;
    return __uint_as_float(x);
}

// ---------------- CSR build ----------------

__global__ void k_hist(const int* __restrict__ dst, int* __restrict__ cnt) {
    int i = blockIdx.x * 256 + threadIdx.x;
    if (i < N_EDGES) atomicAdd(&cnt[dst[i]], 1);
}

// phase A: per-block (256 elems) exclusive scan + block total
__global__ void k_scan_blk(const int* __restrict__ cnt, int* __restrict__ row_ptr,
                           int* __restrict__ blk) {
    int b = blockIdx.x, t = threadIdx.x;
    int i = b * 256 + t;
    int lane = t & 63, wid = t >> 6;
    int v = (i < N_NODES) ? cnt[i] : 0;
    int x = v;
    #pragma unroll
    for (int off = 1; off < 64; off <<= 1) {
        int y = __shfl_up(x, off);
        if (lane >= off) x += y;
    }
    __shared__ int ws[4];
    if (lane == 63) ws[wid] = x;
    __syncthreads();
    if (t == 0) {
        int s = 0;
        #pragma unroll
        for (int j = 0; j < 4; j++) { int tmp = ws[j]; ws[j] = s; s += tmp; }
        blk[b] = s;
    }
    __syncthreads();
    if (i < N_NODES) row_ptr[i] = ws[wid] + x - v;
}

// phase B: exclusive scan of the 196 block totals (1 block)
__global__ void k_scan_tot(int* __restrict__ blk) {
    int t = threadIdx.x;
    int lane = t & 63, wid = t >> 6;
    int v = (t < SCAN_NB) ? blk[t] : 0;
    int x = v;
    #pragma unroll
    for (int off = 1; off < 64; off <<= 1) {
        int y = __shfl_up(x, off);
        if (lane >= off) x += y;
    }
    __shared__ int ws[4];
    if (lane == 63) ws[wid] = x;
    __syncthreads();
    if (t == 0) {
        int s = 0;
        #pragma unroll
        for (int j = 0; j < 4; j++) { int tmp = ws[j]; ws[j] = s; s += tmp; }
    }
    __syncthreads();
    if (t < SCAN_NB) blk[t] = ws[wid] + x - v;
}

// phase C: add block offsets
__global__ void k_scan_add(int* __restrict__ row_ptr, const int* __restrict__ blk) {
    int i = blockIdx.x * 256 + threadIdx.x;
    if (i < N_NODES) row_ptr[i] += blk[i >> 8];
    if (i == 0) row_ptr[N_NODES] = N_EDGES;
}

__global__ void k_scatter(const int* __restrict__ src, const int* __restrict__ dst,
                          const int* __restrict__ row_ptr, int* __restrict__ cnt,
                          int* __restrict__ edge_src) {
    int i = blockIdx.x * 256 + threadIdx.x;
    if (i < N_EDGES) {
        int d = dst[i];
        int pos = row_ptr[d] + atomicAdd(&cnt[d], 1);
        edge_src[pos] = src[i];
    }
}

// ---------------- fp32 -> bf16 convert (inputs) ----------------

__global__ void k_tobf16(const float* __restrict__ x, unsigned short* __restrict__ y) {
    int i = blockIdx.x * 256 + threadIdx.x;   // handles 4 elems
    float4 v = ((const float4*)x)[i];
    ushort4 u;
    u.x = f2bf_u(v.x); u.y = f2bf_u(v.y); u.z = f2bf_u(v.z); u.w = f2bf_u(v.w);
    ((ushort4*)y)[i] = u;
}

// ---------------- aggregation: wave per node, bf16 in/out, fp32 accumulate ----------------

__global__ void k_aggregate_bf(const unsigned short* __restrict__ feat,
                               const int* __restrict__ row_ptr,
                               const int* __restrict__ edge_src,
                               unsigned short* __restrict__ outb) {
    int w = (blockIdx.x * 256 + threadIdx.x) >> 6;
    int lane = threadIdx.x & 63;
    if (w >= N_NODES) return;
    int beg = row_ptr[w], end = row_ptr[w + 1];
    float ax = 0.f, ay = 0.f;
    int e = beg;
    #pragma unroll 1
    for (; e + 4 <= end; e += 4) {
        int s0 = edge_src[e], s1 = edge_src[e + 1], s2 = edge_src[e + 2], s3 = edge_src[e + 3];
        ushort2 v0 = ((const ushort2*)(feat + (size_t)s0 * EMB))[lane];
        ushort2 v1 = ((const ushort2*)(feat + (size_t)s1 * EMB))[lane];
        ushort2 v2 = ((const ushort2*)(feat + (size_t)s2 * EMB))[lane];
        ushort2 v3 = ((const ushort2*)(feat + (size_t)s3 * EMB))[lane];
        ax += bfu2f(v0.x) + bfu2f(v1.x) + bfu2f(v2.x) + bfu2f(v3.x);
        ay += bfu2f(v0.y) + bfu2f(v1.y) + bfu2f(v2.y) + bfu2f(v3.y);
    }
    #pragma unroll 1
    for (; e < end; e++) {
        int s0 = edge_src[e];
        ushort2 v0 = ((const ushort2*)(feat + (size_t)s0 * EMB))[lane];
        ax += bfu2f(v0.x);
        ay += bfu2f(v0.y);
    }
    ushort2 o; o.x = f2bf_u(ax); o.y = f2bf_u(ay);
    ((ushort2*)(outb + (size_t)w * EMB))[lane] = o;
}

// ---------------- GCN linear via MFMA: out[M][128] = act(A[M][128] @ W.T + b) ----------------
// block 256 (4 waves); wave = 16 A-rows x 128 cols (8 n-tiles), K=128 (4 k-steps).
// Fragment convention (validated R2): A,B row-major; lane&15 = free index, k = quad*8+j;
// D[row = quad*4+r (A dim)][col = lane&15 (B dim)].

__global__ void __launch_bounds__(256)
k_gcn_mfma(const unsigned short* __restrict__ Ab,   // [M][128] bf16
           const unsigned short* __restrict__ Wb,   // [128][128] bf16 (torch W: row j = out col)
           const float* __restrict__ bias,          // [128]
           unsigned short* __restrict__ outb,       // [M][128] bf16
           int M, int do_tanh) {
    int tid = threadIdx.x;
    int w = tid >> 6, lane = tid & 63;
    int l16 = lane & 15, quad = lane >> 4;
    int rbase = blockIdx.x * 64 + w * 16;
    int arow = rbase + l16;
    if (arow >= M) arow = M - 1;                    // guarded store below
    const short* Ap = (const short*)Ab + (size_t)arow * 128 + quad * 8;
    const short* Wp = (const short*)Wb;
    f32x4 acc[8] = {};
    #pragma unroll
    for (int ks = 0; ks < 4; ks++) {
        short8 a = *(const short8*)(Ap + ks * 32);
        #pragma unroll
        for (int ct = 0; ct < 8; ct++) {
            short8 b = *(const short8*)(Wp + (size_t)(ct * 16 + l16) * 128 + ks * 32 + quad * 8);
            acc[ct] = __builtin_amdgcn_mfma_f32_16x16x32_bf16(a, b, acc[ct], 0, 0, 0);
        }
    }
    #pragma unroll
    for (int ct = 0; ct < 8; ct++) {
        float bcol = bias[ct * 16 + l16];
        #pragma unroll
        for (int r = 0; r < 4; r++) {
            int row = rbase + quad * 4 + r;
            if (row < M) {
                float v = acc[ct][r] + bcol;
                if (do_tanh) v = tanhf(v);
                outb[(size_t)row * 128 + ct * 16 + l16] = f2bf_u(v);
            }
        }
    }
}

// ---------------- prep: Wcat[1024][384]=bf16(Wi||Wh), bsum=bi+bh, W1b, W2b ----------------

__global__ void k_prep(const float* __restrict__ Wi, const float* __restrict__ Wh,
                       const float* __restrict__ bi, const float* __restrict__ bh,
                       const float* __restrict__ W1, const float* __restrict__ W2,
                       unsigned short* __restrict__ Wcat, float* __restrict__ bsum,
                       unsigned short* __restrict__ W1b, unsigned short* __restrict__ W2b) {
    int idx = blockIdx.x * 256 + threadIdx.x;
    if (idx < 1024 * 384) {
        int r = idx / 384, k = idx - r * 384;
        float v = (k < 128) ? Wi[r * 128 + k] : Wh[r * 256 + (k - 128)];
        Wcat[idx] = f2bf_u(v);
    } else if (idx < 1024 * 384 + 1024) {
        int r = idx - 1024 * 384;
        bsum[r] = bi[r] + bh[r];
    } else if (idx < 1024 * 384 + 1024 + 16384) {
        int r = idx - (1024 * 384 + 1024);
        W1b[r] = f2bf_u(W1[r]);
    } else if (idx < 1024 * 384 + 1024 + 32768) {
        int r = idx - (1024 * 384 + 1024 + 16384);
        W2b[r] = f2bf_u(W2[r]);
    }
}

// ---------------- persistent LSTM: 256 blocks (1/CU), weights register-resident ----------------

__device__ __forceinline__ void gsync(int* cnt, int* gen) {
    __threadfence();                 // release: make this thread's h-writes visible
    __syncthreads();
    if (threadIdx.x == 0) {
        int g = __hip_atomic_load(gen, __ATOMIC_ACQUIRE, __HIP_MEMORY_SCOPE_AGENT);
        int v = __hip_atomic_fetch_add(cnt, 1, __ATOMIC_ACQ_REL, __HIP_MEMORY_SCOPE_AGENT);
        if (v == 255) {
            __hip_atomic_store(cnt, 0, __ATOMIC_RELAXED, __HIP_MEMORY_SCOPE_AGENT);
            __hip_atomic_fetch_add(gen, 1, __ATOMIC_ACQ_REL, __HIP_MEMORY_SCOPE_AGENT);
        } else {
            while (__hip_atomic_load(gen, __ATOMIC_ACQUIRE, __HIP_MEMORY_SCOPE_AGENT) == g)
                __builtin_amdgcn_s_sleep(1);
        }
    }
    __syncthreads();
    __threadfence();                 // acquire: invalidate stale cached h
}

__global__ void __launch_bounds__(256, 1)
k_lstm_persist(const unsigned short* __restrict__ hn_bf,   // [N_NODES][128] bf16
               const unsigned short* __restrict__ Wcat,    // [1024][384] bf16
               const float* __restrict__ bsum,             // [1024]
               const int* __restrict__ sidx,               // [NSENT][MAXLEN]
               const int* __restrict__ lengths,            // [NSENT]
               unsigned short* __restrict__ hA,            // [NSENT][256] bf16 ping
               unsigned short* __restrict__ hB,            // [NSENT][256] bf16 pong
               float* __restrict__ h_last,                 // [NSENT][256] fp32
               int* __restrict__ sync_cnt, int* __restrict__ sync_gen) {
    int tid = threadIdx.x;
    int w = tid >> 6, lane = tid & 63;
    int l16 = lane & 15, quad = lane >> 4;
    int schunk = blockIdx.x & 63;
    int qy = blockIdx.x >> 6;
    int u = qy * 64 + w * 16 + l16;

    // ---- preload all B-fragments into registers (48 x short8 = 192 VGPRs) ----
    short8 Bf[48];                                   // [ks 0..11][g 0..3]
    {
        const short* Wp = (const short*)Wcat;
        #pragma unroll
        for (int g = 0; g < 4; g++) {
            const short* base = Wp + (size_t)(g * 256 + u) * 384 + quad * 8;
            #pragma unroll
            for (int ks = 0; ks < 12; ks++)
                Bf[ks * 4 + g] = *(const short8*)(base + ks * 32);
        }
    }
    float bs[4];
    #pragma unroll
    for (int g = 0; g < 4; g++) bs[g] = bsum[g * 256 + u];

    int len_r[8];                                    // [mt*4+r]
    #pragma unroll
    for (int mt = 0; mt < 2; mt++)
        #pragma unroll
        for (int r = 0; r < 4; r++)
            len_r[mt * 4 + r] = lengths[schunk * 32 + mt * 16 + quad * 4 + r];

    const int* sidx0 = sidx + (size_t)(schunk * 32 + l16) * MAXLEN;
    const int* sidx1 = sidx + (size_t)(schunk * 32 + 16 + l16) * MAXLEN;
    const short* hnp = (const short*)hn_bf;
    size_t hofs0 = (size_t)(schunk * 32 + l16) * 256 + quad * 8;
    size_t hofs1 = (size_t)(schunk * 32 + 16 + l16) * 256 + quad * 8;

    float c_reg[8] = {0.f, 0.f, 0.f, 0.f, 0.f, 0.f, 0.f, 0.f};

    #pragma unroll 1
    for (int t = 0; t < MAXLEN; t++) {
        unsigned short* hout = (t & 1) ? hB : hA;
        const unsigned short* hin = (t & 1) ? hA : hB;

        int nid0 = sidx0[t];
        int nid1 = sidx1[t];
        const short* Ax0 = hnp + (size_t)nid0 * 128 + quad * 8;
        const short* Ax1 = hnp + (size_t)nid1 * 128 + quad * 8;

        f32x4 acc[8] = {};                           // [mt*4+g]

        // X phase: K=128 (4 k-steps)
        #pragma unroll
        for (int ks = 0; ks < 4; ks++) {
            short8 a0 = *(const short8*)(Ax0 + ks * 32);
            short8 a1 = *(const short8*)(Ax1 + ks * 32);
            #pragma unroll
            for (int g = 0; g < 4; g++) {
                acc[g]     = __builtin_amdgcn_mfma_f32_16x16x32_bf16(a0, Bf[ks * 4 + g], acc[g], 0, 0, 0);
                acc[4 + g] = __builtin_amdgcn_mfma_f32_16x16x32_bf16(a1, Bf[ks * 4 + g], acc[4 + g], 0, 0, 0);
            }
        }
        // H phase: K=256 (8 k-steps); h_prev == 0 at t=0
        if (t > 0) {
            const short* Ah0 = (const short*)hin + hofs0;
            const short* Ah1 = (const short*)hin + hofs1;
            #pragma unroll
            for (int ks = 0; ks < 8; ks++) {
                short8 a0 = *(const short8*)(Ah0 + ks * 32);
                short8 a1 = *(const short8*)(Ah1 + ks * 32);
                #pragma unroll
                for (int g = 0; g < 4; g++) {
                    acc[g]     = __builtin_amdgcn_mfma_f32_16x16x32_bf16(a0, Bf[(4 + ks) * 4 + g], acc[g], 0, 0, 0);
                    acc[4 + g] = __builtin_amdgcn_mfma_f32_16x16x32_bf16(a1, Bf[(4 + ks) * 4 + g], acc[4 + g], 0, 0, 0);
                }
            }
        }

        // epilogue: per-lane pointwise update; c stays in registers
        #pragma unroll
        for (int mt = 0; mt < 2; mt++) {
            #pragma unroll
            for (int r = 0; r < 4; r++) {
                int mloc = mt * 16 + quad * 4 + r;
                int m = schunk * 32 + mloc;
                float gi = acc[mt * 4 + 0][r] + bs[0];
                float gf = acc[mt * 4 + 1][r] + bs[1];
                float gg = acc[mt * 4 + 2][r] + bs[2];
                float go = acc[mt * 4 + 3][r] + bs[3];
                float i_ = 1.f / (1.f + expf(-gi));
                float f_ = 1.f / (1.f + expf(-gf));
                float g_ = tanhf(gg);
                float o_ = 1.f / (1.f + expf(-go));
                float c = f_ * c_reg[mt * 4 + r] + i_ * g_;
                c_reg[mt * 4 + r] = c;
                float h = o_ * tanhf(c);
                size_t off = (size_t)m * 256 + u;
                hout[off] = f2bf_u(h);
                if (len_r[mt * 4 + r] - 1 == t) h_last[off] = h;
            }
        }

        if (t < MAXLEN - 1) gsync(sync_cnt, sync_gen);
    }
}

// ---------------- classifier ----------------

__global__ void k_classifier(const float* __restrict__ h_last,
                             const float* __restrict__ Wc1, const float* __restrict__ bc1,
                             const float* __restrict__ Wc2, const float* __restrict__ bc2,
                             float* __restrict__ out) {
    int lane = threadIdx.x & 63;
    int wslot = threadIdx.x >> 6;
    int s = blockIdx.x * 4 + wslot;
    __shared__ float e_sh[4][256];
    const float* hr = h_last + (size_t)s * 256;
    #pragma unroll
    for (int i = 0; i < 4; i++) {
        float v = hr[lane + 64 * i];
        e_sh[wslot][lane + 64 * i] = fmaxf(v, 0.f);
    }
    __syncthreads();
    float zpart = 0.f;
    #pragma unroll
    for (int jj = 0; jj < 2; jj++) {
        int j = lane + 64 * jj;
        float a = bc1[j];
        const float4* wr = (const float4*)(Wc1 + (size_t)j * 256);
        #pragma unroll 8
        for (int k4 = 0; k4 < 64; k4++) {
            float4 wv = wr[k4];
            float4 e = *(const float4*)&e_sh[wslot][k4 * 4];
            a += wv.x * e.x + wv.y * e.y + wv.z * e.z + wv.w * e.w;
        }
        a = fmaxf(a, 0.f);
        zpart += a * Wc2[j];
    }
    #pragma unroll
    for (int off = 32; off > 0; off >>= 1) zpart += __shfl_down(zpart, off);
    if (lane == 0) out[s] = zpart + bc2[0];
}

// ---------------- launcher ----------------

extern "C" void kernel_launch(void* const* d_in, const int* in_sizes, int n_in,
                              void* d_out, int out_size, void* d_ws, size_t ws_size,
                              hipStream_t stream) {
    const float* inputs = (const float*)d_in[0];
    const float* W1  = (const float*)d_in[1];
    const float* b1  = (const float*)d_in[2];
    const float* W2  = (const float*)d_in[3];
    const float* b2  = (const float*)d_in[4];
    const float* Wi  = (const float*)d_in[5];
    const float* Wh  = (const float*)d_in[6];
    const float* bi  = (const float*)d_in[7];
    const float* bh  = (const float*)d_in[8];
    const float* Wc1 = (const float*)d_in[9];
    const float* bc1 = (const float*)d_in[10];
    const float* Wc2 = (const float*)d_in[11];
    const float* bc2 = (const float*)d_in[12];
    const int* src      = (const int*)d_in[13];
    const int* dst      = (const int*)d_in[14];
    const int* sidx     = (const int*)d_in[15];
    const int* lengths  = (const int*)d_in[16];
    float* out = (float*)d_out;

    char* ws = (char*)d_ws;
    size_t off = 0;
    auto alloc = [&](size_t bytes) -> void* {
        void* p = ws + off;
        off = (off + bytes + 255) & ~(size_t)255;
        return p;
    };
    unsigned short* in_bf  = (unsigned short*)alloc(2 * (size_t)N_NODES * EMB);
    unsigned short* agg_bf = (unsigned short*)alloc(2 * (size_t)N_NODES * EMB);
    unsigned short* h_bf   = (unsigned short*)alloc(2 * (size_t)N_NODES * EMB);
    unsigned short* hn_bf  = (unsigned short*)alloc(2 * (size_t)N_NODES * EMB);
    int*   row_ptr  = (int*)alloc(sizeof(int) * (N_NODES + 1));
    int*   cnt      = (int*)alloc(sizeof(int) * N_NODES);
    int*   blk      = (int*)alloc(sizeof(int) * SCAN_NB);
    int*   edge_src = (int*)alloc(sizeof(int) * N_EDGES);
    unsigned short* Wcat = (unsigned short*)alloc(2 * 1024 * 384);
    unsigned short* W1b  = (unsigned short*)alloc(2 * 128 * 128);
    unsigned short* W2b  = (unsigned short*)alloc(2 * 128 * 128);
    float* bsum     = (float*)alloc(sizeof(float) * 1024);
    unsigned short* hA = (unsigned short*)alloc(2 * NSENT * LH);
    unsigned short* hB = (unsigned short*)alloc(2 * NSENT * LH);
    float* hlast    = (float*)alloc(sizeof(float) * NSENT * LH);
    int*   syncv    = (int*)alloc(sizeof(int) * 2);

    // weight prep (independent of everything else)
    k_prep<<<(1024 * 384 + 1024 + 32768 + 255) / 256, 256, 0, stream>>>(
        Wi, Wh, bi, bh, W1, W2, Wcat, bsum, W1b, W2b);

    // CSR build
    hipMemsetAsync(cnt, 0, sizeof(int) * N_NODES, stream);
    k_hist<<<(N_EDGES + 255) / 256, 256, 0, stream>>>(dst, cnt);
    k_scan_blk<<<SCAN_NB, 256, 0, stream>>>(cnt, row_ptr, blk);
    k_scan_tot<<<1, 256, 0, stream>>>(blk);
    k_scan_add<<<SCAN_NB, 256, 0, stream>>>(row_ptr, blk);
    hipMemsetAsync(cnt, 0, sizeof(int) * N_NODES, stream);
    k_scatter<<<(N_EDGES + 255) / 256, 256, 0, stream>>>(src, dst, row_ptr, cnt, edge_src);

    // GCN (bf16 path)
    k_tobf16<<<(N_NODES * EMB / 4 + 255) / 256, 256, 0, stream>>>(inputs, in_bf);
    k_aggregate_bf<<<(N_NODES * 64) / 256, 256, 0, stream>>>(in_bf, row_ptr, edge_src, agg_bf);
    k_gcn_mfma<<<(N_NODES + 63) / 64, 256, 0, stream>>>(agg_bf, W1b, b1, h_bf, N_NODES, 1);
    k_aggregate_bf<<<(N_NODES * 64) / 256, 256, 0, stream>>>(h_bf, row_ptr, edge_src, agg_bf);
    k_gcn_mfma<<<(N_NODES + 63) / 64, 256, 0, stream>>>(agg_bf, W2b, b2, hn_bf, N_NODES, 0);

    // persistent LSTM (single launch, manual grid sync)
    hipMemsetAsync(syncv, 0, sizeof(int) * 2, stream);
    k_lstm_persist<<<256, 256, 0, stream>>>(hn_bf, Wcat, bsum, sidx, lengths,
                                            hA, hB, hlast, syncv, syncv + 1);

    // classifier
    k_classifier<<<NSENT / 4, 256, 0, stream>>>(hlast, Wc1, bc1, Wc2, bc2, out);
}

// Round 4
// 898.288 us; speedup vs baseline: 2.4666x; 2.4666x over previous
//
#include <hip/hip_runtime.h>
#include <hip/hip_bf16.h>
#include <math.h>

#define N_NODES 50000
#define N_EDGES 800000
#define EMB 128
#define LH 256
#define NSENT 2048
#define MAXLEN 32
#define SCAN_NB 196   // ceil(50000/256)

typedef __attribute__((ext_vector_type(8))) short short8;
typedef __attribute__((ext_vector_type(4))) float f32x4;

__device__ __forceinline__ unsigned short f2bf_u(float f) {
    __hip_bfloat16 h = __float2bfloat16(f);
    return *reinterpret_cast<unsigned short*>(&h);
}
__device__ __forceinline__ float bfu2f(unsigned short u) {
    unsigned int x = ((unsigned int)u) << 16;
    return __uint_as_float(x);
}

// ---------------- CSR build ----------------

__global__ void k_hist(const int* __restrict__ dst, int* __restrict__ cnt) {
    int i = blockIdx.x * 256 + threadIdx.x;
    if (i < N_EDGES) atomicAdd(&cnt[dst[i]], 1);
}

__global__ void k_scan_blk(const int* __restrict__ cnt, int* __restrict__ row_ptr,
                           int* __restrict__ blk) {
    int b = blockIdx.x, t = threadIdx.x;
    int i = b * 256 + t;
    int lane = t & 63, wid = t >> 6;
    int v = (i < N_NODES) ? cnt[i] : 0;
    int x = v;
    #pragma unroll
    for (int off = 1; off < 64; off <<= 1) {
        int y = __shfl_up(x, off);
        if (lane >= off) x += y;
    }
    __shared__ int ws[4];
    if (lane == 63) ws[wid] = x;
    __syncthreads();
    if (t == 0) {
        int s = 0;
        #pragma unroll
        for (int j = 0; j < 4; j++) { int tmp = ws[j]; ws[j] = s; s += tmp; }
        blk[b] = s;
    }
    __syncthreads();
    if (i < N_NODES) row_ptr[i] = ws[wid] + x - v;
}

__global__ void k_scan_tot(int* __restrict__ blk) {
    int t = threadIdx.x;
    int lane = t & 63, wid = t >> 6;
    int v = (t < SCAN_NB) ? blk[t] : 0;
    int x = v;
    #pragma unroll
    for (int off = 1; off < 64; off <<= 1) {
        int y = __shfl_up(x, off);
        if (lane >= off) x += y;
    }
    __shared__ int ws[4];
    if (lane == 63) ws[wid] = x;
    __syncthreads();
    if (t == 0) {
        int s = 0;
        #pragma unroll
        for (int j = 0; j < 4; j++) { int tmp = ws[j]; ws[j] = s; s += tmp; }
    }
    __syncthreads();
    if (t < SCAN_NB) blk[t] = ws[wid] + x - v;
}

__global__ void k_scan_add(int* __restrict__ row_ptr, const int* __restrict__ blk) {
    int i = blockIdx.x * 256 + threadIdx.x;
    if (i < N_NODES) row_ptr[i] += blk[i >> 8];
    if (i == 0) row_ptr[N_NODES] = N_EDGES;
}

__global__ void k_scatter(const int* __restrict__ src, const int* __restrict__ dst,
                          const int* __restrict__ row_ptr, int* __restrict__ cnt,
                          int* __restrict__ edge_src) {
    int i = blockIdx.x * 256 + threadIdx.x;
    if (i < N_EDGES) {
        int d = dst[i];
        int pos = row_ptr[d] + atomicAdd(&cnt[d], 1);
        edge_src[pos] = src[i];
    }
}

// ---------------- fp32 -> bf16 convert (inputs) ----------------

__global__ void k_tobf16(const float* __restrict__ x, unsigned short* __restrict__ y) {
    int i = blockIdx.x * 256 + threadIdx.x;
    float4 v = ((const float4*)x)[i];
    ushort4 u;
    u.x = f2bf_u(v.x); u.y = f2bf_u(v.y); u.z = f2bf_u(v.z); u.w = f2bf_u(v.w);
    ((ushort4*)y)[i] = u;
}

// ---------------- aggregation: wave per node, bf16 in/out, fp32 accumulate ----------------

__global__ void k_aggregate_bf(const unsigned short* __restrict__ feat,
                               const int* __restrict__ row_ptr,
                               const int* __restrict__ edge_src,
                               unsigned short* __restrict__ outb) {
    int w = (blockIdx.x * 256 + threadIdx.x) >> 6;
    int lane = threadIdx.x & 63;
    if (w >= N_NODES) return;
    int beg = row_ptr[w], end = row_ptr[w + 1];
    float ax = 0.f, ay = 0.f;
    int e = beg;
    #pragma unroll 1
    for (; e + 4 <= end; e += 4) {
        int s0 = edge_src[e], s1 = edge_src[e + 1], s2 = edge_src[e + 2], s3 = edge_src[e + 3];
        ushort2 v0 = ((const ushort2*)(feat + (size_t)s0 * EMB))[lane];
        ushort2 v1 = ((const ushort2*)(feat + (size_t)s1 * EMB))[lane];
        ushort2 v2 = ((const ushort2*)(feat + (size_t)s2 * EMB))[lane];
        ushort2 v3 = ((const ushort2*)(feat + (size_t)s3 * EMB))[lane];
        ax += bfu2f(v0.x) + bfu2f(v1.x) + bfu2f(v2.x) + bfu2f(v3.x);
        ay += bfu2f(v0.y) + bfu2f(v1.y) + bfu2f(v2.y) + bfu2f(v3.y);
    }
    #pragma unroll 1
    for (; e < end; e++) {
        int s0 = edge_src[e];
        ushort2 v0 = ((const ushort2*)(feat + (size_t)s0 * EMB))[lane];
        ax += bfu2f(v0.x);
        ay += bfu2f(v0.y);
    }
    ushort2 o; o.x = f2bf_u(ax); o.y = f2bf_u(ay);
    ((ushort2*)(outb + (size_t)w * EMB))[lane] = o;
}

// ---------------- GCN linear via MFMA ----------------

__global__ void __launch_bounds__(256)
k_gcn_mfma(const unsigned short* __restrict__ Ab,   // [M][128] bf16
           const unsigned short* __restrict__ Wb,   // [128][128] bf16
           const float* __restrict__ bias,
           unsigned short* __restrict__ outb,
           int M, int do_tanh) {
    int tid = threadIdx.x;
    int w = tid >> 6, lane = tid & 63;
    int l16 = lane & 15, quad = lane >> 4;
    int rbase = blockIdx.x * 64 + w * 16;
    int arow = rbase + l16;
    if (arow >= M) arow = M - 1;
    const short* Ap = (const short*)Ab + (size_t)arow * 128 + quad * 8;
    const short* Wp = (const short*)Wb;
    f32x4 acc[8] = {};
    #pragma unroll
    for (int ks = 0; ks < 4; ks++) {
        short8 a = *(const short8*)(Ap + ks * 32);
        #pragma unroll
        for (int ct = 0; ct < 8; ct++) {
            short8 b = *(const short8*)(Wp + (size_t)(ct * 16 + l16) * 128 + ks * 32 + quad * 8);
            acc[ct] = __builtin_amdgcn_mfma_f32_16x16x32_bf16(a, b, acc[ct], 0, 0, 0);
        }
    }
    #pragma unroll
    for (int ct = 0; ct < 8; ct++) {
        float bcol = bias[ct * 16 + l16];
        #pragma unroll
        for (int r = 0; r < 4; r++) {
            int row = rbase + quad * 4 + r;
            if (row < M) {
                float v = acc[ct][r] + bcol;
                if (do_tanh) v = tanhf(v);
                outb[(size_t)row * 128 + ct * 16 + l16] = f2bf_u(v);
            }
        }
    }
}

// ---------------- prep: Wpk (fragment-linear packed LSTM weights), bsum, W1b, W2b ----------------
// Wpk layout: for ct in [0,64) (16 gate-rows per tile), ks in [0,12) (32 K per step):
//   512 shorts at ((ct*12+ks)<<9), element (lane*8 + jj) = W[ct*16 + (lane&15)][ks*32 + (lane>>4)*8 + jj]
// -> a wave's B-fragment load is one fully-coalesced 1KB global_load_dwordx4.

__global__ void k_prep(const float* __restrict__ Wi, const float* __restrict__ Wh,
                       const float* __restrict__ bi, const float* __restrict__ bh,
                       const float* __restrict__ W1, const float* __restrict__ W2,
                       unsigned short* __restrict__ Wpk, float* __restrict__ bsum,
                       unsigned short* __restrict__ W1b, unsigned short* __restrict__ W2b) {
    int idx = blockIdx.x * 256 + threadIdx.x;
    if (idx < 1024 * 384) {
        int R = idx / 384, k = idx - R * 384;
        float v = (k < 128) ? Wi[R * 128 + k] : Wh[R * 256 + (k - 128)];
        int ct = R >> 4, cin = R & 15;
        int ks = k >> 5, kk = k & 31;
        int q = kk >> 3, jj = kk & 7;
        Wpk[((ct * 12 + ks) << 9) + (q * 16 + cin) * 8 + jj] = f2bf_u(v);
    } else if (idx < 1024 * 384 + 1024) {
        int r = idx - 1024 * 384;
        bsum[r] = bi[r] + bh[r];
    } else if (idx < 1024 * 384 + 1024 + 16384) {
        int r = idx - (1024 * 384 + 1024);
        W1b[r] = f2bf_u(W1[r]);
    } else if (idx < 1024 * 384 + 1024 + 32768) {
        int r = idx - (1024 * 384 + 1024 + 16384);
        W2b[r] = f2bf_u(W2[r]);
    }
}

// ---------------- LSTM: 64 self-contained blocks, h in LDS, zero inter-block comm ----------------
// Block b owns sentences [b*32, b*32+32) fully (all 256 units). 512 threads = 8 waves;
// wave w computes units [w*32, w*32+32) for all 4 gates (n-tiles ct = g*16 + w*2 + us).
// h double-buffers in LDS (pad +8 units -> 2-way-max bank aliasing, 16B-aligned rows);
// c stays in registers; weights stream from XCD L2 (768KB/step/CU = the design's floor).

#define HPITCH 264   // 256 + 8 pad (keeps 528B row stride, multiple of 16B)

__global__ void __launch_bounds__(512, 2)
k_lstm_block(const unsigned short* __restrict__ hn_bf,   // [N_NODES][128] bf16
             const unsigned short* __restrict__ Wpk,     // packed, see k_prep
             const float* __restrict__ bsum,             // [1024]
             const int* __restrict__ sidx,               // [NSENT][MAXLEN]
             const int* __restrict__ lengths,            // [NSENT]
             float* __restrict__ h_last) {               // [NSENT][256] fp32
    __shared__ unsigned short hsh[2][32 * HPITCH];
    __shared__ int nid_sh[32 * 32];   // [m][t]
    __shared__ int len_sh[32];
    int tid = threadIdx.x;
    int w = tid >> 6, lane = tid & 63;
    int l16 = lane & 15, quad = lane >> 4;
    int s0 = blockIdx.x * 32;

    for (int i = tid; i < 32 * 32; i += 512)
        nid_sh[i] = sidx[(size_t)(s0 + (i >> 5)) * MAXLEN + (i & 31)];
    if (tid < 32) len_sh[tid] = lengths[s0 + tid];
    __syncthreads();

    float bs[4][2];
    #pragma unroll
    for (int g = 0; g < 4; g++)
        #pragma unroll
        for (int us = 0; us < 2; us++)
            bs[g][us] = bsum[g * 256 + w * 32 + us * 16 + l16];

    float c_reg[2][2][4] = {};   // [mt][us][r]
    const short* hnp = (const short*)hn_bf;
    const short* Wp = (const short*)Wpk;

    #pragma unroll 1
    for (int t = 0; t < MAXLEN; t++) {
        const short* hin = (const short*)hsh[t & 1];
        unsigned short* hout = hsh[(t & 1) ^ 1];

        f32x4 acc[2][8] = {};   // [mt][g*2+us]

        int nid0 = nid_sh[l16 * 32 + t];
        int nid1 = nid_sh[(16 + l16) * 32 + t];
        const short* Ax0 = hnp + (size_t)nid0 * 128 + quad * 8;
        const short* Ax1 = hnp + (size_t)nid1 * 128 + quad * 8;

        // X phase: gates += x_t @ Wi.T  (ks 0..3)
        #pragma unroll 2
        for (int ks = 0; ks < 4; ks++) {
            short8 a0 = *(const short8*)(Ax0 + ks * 32);
            short8 a1 = *(const short8*)(Ax1 + ks * 32);
            #pragma unroll
            for (int g = 0; g < 4; g++)
                #pragma unroll
                for (int us = 0; us < 2; us++) {
                    int ct = g * 16 + w * 2 + us;
                    short8 b = *(const short8*)(Wp + ((ct * 12 + ks) << 9) + lane * 8);
                    acc[0][g * 2 + us] = __builtin_amdgcn_mfma_f32_16x16x32_bf16(a0, b, acc[0][g * 2 + us], 0, 0, 0);
                    acc[1][g * 2 + us] = __builtin_amdgcn_mfma_f32_16x16x32_bf16(a1, b, acc[1][g * 2 + us], 0, 0, 0);
                }
        }
        // H phase: gates += h_prev @ Wh.T  (ks 4..11, A from LDS); h_prev==0 at t=0
        if (t > 0) {
            #pragma unroll 2
            for (int ks = 0; ks < 8; ks++) {
                short8 a0 = *(const short8*)(hin + l16 * HPITCH + ks * 32 + quad * 8);
                short8 a1 = *(const short8*)(hin + (16 + l16) * HPITCH + ks * 32 + quad * 8);
                #pragma unroll
                for (int g = 0; g < 4; g++)
                    #pragma unroll
                    for (int us = 0; us < 2; us++) {
                        int ct = g * 16 + w * 2 + us;
                        short8 b = *(const short8*)(Wp + ((ct * 12 + 4 + ks) << 9) + lane * 8);
                        acc[0][g * 2 + us] = __builtin_amdgcn_mfma_f32_16x16x32_bf16(a0, b, acc[0][g * 2 + us], 0, 0, 0);
                        acc[1][g * 2 + us] = __builtin_amdgcn_mfma_f32_16x16x32_bf16(a1, b, acc[1][g * 2 + us], 0, 0, 0);
                    }
            }
        }

        // epilogue: per-lane pointwise update; c in registers; h -> LDS (+ h_last if end)
        #pragma unroll
        for (int mt = 0; mt < 2; mt++)
            #pragma unroll
            for (int us = 0; us < 2; us++)
                #pragma unroll
                for (int r = 0; r < 4; r++) {
                    int m = mt * 16 + quad * 4 + r;
                    int u = w * 32 + us * 16 + l16;
                    float gi = acc[mt][0 * 2 + us][r] + bs[0][us];
                    float gf = acc[mt][1 * 2 + us][r] + bs[1][us];
                    float gg = acc[mt][2 * 2 + us][r] + bs[2][us];
                    float go = acc[mt][3 * 2 + us][r] + bs[3][us];
                    float i_ = 1.f / (1.f + expf(-gi));
                    float f_ = 1.f / (1.f + expf(-gf));
                    float g_ = tanhf(gg);
                    float o_ = 1.f / (1.f + expf(-go));
                    float c = f_ * c_reg[mt][us][r] + i_ * g_;
                    c_reg[mt][us][r] = c;
                    float h = o_ * tanhf(c);
                    hout[m * HPITCH + u] = f2bf_u(h);
                    if (len_sh[m] - 1 == t) h_last[(size_t)(s0 + m) * 256 + u] = h;
                }
        __syncthreads();
    }
}

// ---------------- classifier ----------------

__global__ void k_classifier(const float* __restrict__ h_last,
                             const float* __restrict__ Wc1, const float* __restrict__ bc1,
                             const float* __restrict__ Wc2, const float* __restrict__ bc2,
                             float* __restrict__ out) {
    int lane = threadIdx.x & 63;
    int wslot = threadIdx.x >> 6;
    int s = blockIdx.x * 4 + wslot;
    __shared__ float e_sh[4][256];
    const float* hr = h_last + (size_t)s * 256;
    #pragma unroll
    for (int i = 0; i < 4; i++) {
        float v = hr[lane + 64 * i];
        e_sh[wslot][lane + 64 * i] = fmaxf(v, 0.f);
    }
    __syncthreads();
    float zpart = 0.f;
    #pragma unroll
    for (int jj = 0; jj < 2; jj++) {
        int j = lane + 64 * jj;
        float a = bc1[j];
        const float4* wr = (const float4*)(Wc1 + (size_t)j * 256);
        #pragma unroll 8
        for (int k4 = 0; k4 < 64; k4++) {
            float4 wv = wr[k4];
            float4 e = *(const float4*)&e_sh[wslot][k4 * 4];
            a += wv.x * e.x + wv.y * e.y + wv.z * e.z + wv.w * e.w;
        }
        a = fmaxf(a, 0.f);
        zpart += a * Wc2[j];
    }
    #pragma unroll
    for (int off = 32; off > 0; off >>= 1) zpart += __shfl_down(zpart, off);
    if (lane == 0) out[s] = zpart + bc2[0];
}

// ---------------- launcher ----------------

extern "C" void kernel_launch(void* const* d_in, const int* in_sizes, int n_in,
                              void* d_out, int out_size, void* d_ws, size_t ws_size,
                              hipStream_t stream) {
    const float* inputs = (const float*)d_in[0];
    const float* W1  = (const float*)d_in[1];
    const float* b1  = (const float*)d_in[2];
    const float* W2  = (const float*)d_in[3];
    const float* b2  = (const float*)d_in[4];
    const float* Wi  = (const float*)d_in[5];
    const float* Wh  = (const float*)d_in[6];
    const float* bi  = (const float*)d_in[7];
    const float* bh  = (const float*)d_in[8];
    const float* Wc1 = (const float*)d_in[9];
    const float* bc1 = (const float*)d_in[10];
    const float* Wc2 = (const float*)d_in[11];
    const float* bc2 = (const float*)d_in[12];
    const int* src      = (const int*)d_in[13];
    const int* dst      = (const int*)d_in[14];
    const int* sidx     = (const int*)d_in[15];
    const int* lengths  = (const int*)d_in[16];
    float* out = (float*)d_out;

    char* ws = (char*)d_ws;
    size_t off = 0;
    auto alloc = [&](size_t bytes) -> void* {
        void* p = ws + off;
        off = (off + bytes + 255) & ~(size_t)255;
        return p;
    };
    unsigned short* in_bf  = (unsigned short*)alloc(2 * (size_t)N_NODES * EMB);
    unsigned short* agg_bf = (unsigned short*)alloc(2 * (size_t)N_NODES * EMB);
    unsigned short* h_bf   = (unsigned short*)alloc(2 * (size_t)N_NODES * EMB);
    unsigned short* hn_bf  = (unsigned short*)alloc(2 * (size_t)N_NODES * EMB);
    int*   row_ptr  = (int*)alloc(sizeof(int) * (N_NODES + 1));
    int*   cnt      = (int*)alloc(sizeof(int) * N_NODES);
    int*   blk      = (int*)alloc(sizeof(int) * SCAN_NB);
    int*   edge_src = (int*)alloc(sizeof(int) * N_EDGES);
    unsigned short* Wpk  = (unsigned short*)alloc(2 * 1024 * 384);
    unsigned short* W1b  = (unsigned short*)alloc(2 * 128 * 128);
    unsigned short* W2b  = (unsigned short*)alloc(2 * 128 * 128);
    float* bsum     = (float*)alloc(sizeof(float) * 1024);
    float* hlast    = (float*)alloc(sizeof(float) * NSENT * LH);

    // weight prep (independent of everything else)
    k_prep<<<(1024 * 384 + 1024 + 32768 + 255) / 256, 256, 0, stream>>>(
        Wi, Wh, bi, bh, W1, W2, Wpk, bsum, W1b, W2b);

    // CSR build
    hipMemsetAsync(cnt, 0, sizeof(int) * N_NODES, stream);
    k_hist<<<(N_EDGES + 255) / 256, 256, 0, stream>>>(dst, cnt);
    k_scan_blk<<<SCAN_NB, 256, 0, stream>>>(cnt, row_ptr, blk);
    k_scan_tot<<<1, 256, 0, stream>>>(blk);
    k_scan_add<<<SCAN_NB, 256, 0, stream>>>(row_ptr, blk);
    hipMemsetAsync(cnt, 0, sizeof(int) * N_NODES, stream);
    k_scatter<<<(N_EDGES + 255) / 256, 256, 0, stream>>>(src, dst, row_ptr, cnt, edge_src);

    // GCN (bf16 path)
    k_tobf16<<<(N_NODES * EMB / 4 + 255) / 256, 256, 0, stream>>>(inputs, in_bf);
    k_aggregate_bf<<<(N_NODES * 64) / 256, 256, 0, stream>>>(in_bf, row_ptr, edge_src, agg_bf);
    k_gcn_mfma<<<(N_NODES + 63) / 64, 256, 0, stream>>>(agg_bf, W1b, b1, h_bf, N_NODES, 1);
    k_aggregate_bf<<<(N_NODES * 64) / 256, 256, 0, stream>>>(h_bf, row_ptr, edge_src, agg_bf);
    k_gcn_mfma<<<(N_NODES + 63) / 64, 256, 0, stream>>>(agg_bf, W2b, b2, hn_bf, N_NODES, 0);

    // LSTM: 64 self-contained blocks, no inter-block sync
    k_lstm_block<<<64, 512, 0, stream>>>(hn_bf, Wpk, bsum, sidx, lengths, hlast);

    // classifier
    k_classifier<<<NSENT / 4, 256, 0, stream>>>(hlast, Wc1, bc1, Wc2, bc2, out);
}